// Round 8
// baseline (1600.187 us; speedup 1.0000x reference)
//
#include <hip/hip_runtime.h>
#include <hip/hip_bf16.h>

#define N_ATOMS 10000
#define N_EDGES 320000
#define H 256
#define H3 768
#define N_RBF 20
#define LN_EPS 1e-5f

typedef __attribute__((ext_vector_type(8))) short bf16x8;
typedef __attribute__((ext_vector_type(4))) float f32x4;
#define MFMA16 __builtin_amdgcn_mfma_f32_16x16x32_bf16

__device__ __forceinline__ float silu_f(float x) { return x / (1.f + __expf(-x)); }

__device__ __forceinline__ unsigned short f2bf(float x) {
    union { float f; unsigned u; } v; v.f = x;
    unsigned r = v.u + 0x7fff + ((v.u >> 16) & 1);
    return (unsigned short)(r >> 16);
}
__device__ __forceinline__ float bf2f(unsigned short b) {
    union { unsigned u; float f; } v; v.u = ((unsigned)b) << 16; return v.f;
}

// ---------------- LayerNorm: one block (256 thr) per atom ----------------
__global__ __launch_bounds__(256) void k_ln(const float* __restrict__ s,
                                            const float* __restrict__ g,
                                            const float* __restrict__ b,
                                            float* __restrict__ sn) {
    int a = blockIdx.x, t = threadIdx.x;
    float x = s[(size_t)a * H + t];
    __shared__ float red[4];
    float v = x;
    for (int o = 32; o > 0; o >>= 1) v += __shfl_down(v, o);
    if ((t & 63) == 0) red[t >> 6] = v;
    __syncthreads();
    float mu = (red[0] + red[1] + red[2] + red[3]) * (1.f / H);
    float dx = x - mu;
    __syncthreads();
    v = dx * dx;
    for (int o = 32; o > 0; o >>= 1) v += __shfl_down(v, o);
    if ((t & 63) == 0) red[t >> 6] = v;
    __syncthreads();
    float var = (red[0] + red[1] + red[2] + red[3]) * (1.f / H);
    float rs = rsqrtf(var + LN_EPS);
    sn[(size_t)a * H + t] = dx * rs * g[t] + b[t];
}

// ---------------- fp32 tiled GEMM: C = [silu](A@B + bias) ----------------
template <int DO_SILU, int IN_BF16, int OUT_BF16>
__global__ __launch_bounds__(256) void k_gemm(const void* __restrict__ Av,
                                              const float* __restrict__ B,
                                              const float* __restrict__ bias,
                                              void* __restrict__ Cv,
                                              int M, int N, int K) {
    const int BM = 64, BN = 64, BK = 16;
    __shared__ float As[BK][BM + 1];
    __shared__ float Bs[BK][BN + 1];
    int tid = threadIdx.x;
    int m0 = blockIdx.x * BM, n0 = blockIdx.y * BN;
    int ty = tid >> 4, tx = tid & 15;
    float acc[4][4] = {};
    for (int k0 = 0; k0 < K; k0 += BK) {
        {
            int kk = tid & 15, mm = tid >> 4;
            for (int r = 0; r < 4; r++) {
                int m = mm + r * 16;
                int gm = m0 + m;
                float a = 0.f;
                if (gm < M) {
                    if (IN_BF16) a = bf2f(((const unsigned short*)Av)[(size_t)gm * K + k0 + kk]);
                    else         a = ((const float*)Av)[(size_t)gm * K + k0 + kk];
                }
                As[kk][m] = a;
            }
        }
        {
            int n = tid & 63, kk = tid >> 6;
            for (int r = 0; r < 4; r++) {
                int k = kk + r * 4;
                Bs[k][n] = B[(size_t)(k0 + k) * N + n0 + n];
            }
        }
        __syncthreads();
        for (int k = 0; k < BK; k++) {
            float a[4], bb[4];
            for (int i = 0; i < 4; i++) a[i] = As[k][ty * 4 + i];
            for (int j = 0; j < 4; j++) bb[j] = Bs[k][tx * 4 + j];
            for (int i = 0; i < 4; i++)
                for (int j = 0; j < 4; j++) acc[i][j] += a[i] * bb[j];
        }
        __syncthreads();
    }
    for (int i = 0; i < 4; i++) {
        int gm = m0 + ty * 4 + i;
        if (gm >= M) continue;
        for (int j = 0; j < 4; j++) {
            int gn = n0 + tx * 4 + j;
            float y = acc[i][j] + bias[gn];
            if (DO_SILU) y = silu_f(y);
            if (OUT_BF16) ((unsigned short*)Cv)[(size_t)gm * N + gn] = f2bf(y);
            else          ((float*)Cv)[(size_t)gm * N + gn] = y;
        }
    }
}

// ---------------- weight prep ----------------
__global__ __launch_bounds__(256) void k_prep_fw2t2(const float* __restrict__ fw2,
                                                    unsigned short* __restrict__ fw2t2) {
    int n = blockIdx.x, k = threadIdx.x;
    float wv = fw2[(size_t)k * H3 + n];
    unsigned short hi = f2bf(wv);
    unsigned short lo = f2bf(wv - bf2f(hi));
    fw2t2[(size_t)n * 512 + k] = hi;
    fw2t2[(size_t)n * 512 + 256 + k] = lo;
}
__global__ __launch_bounds__(256) void k_prep_fw1t2(const float* __restrict__ fw1,
                                                    unsigned short* __restrict__ fw1t2) {
    int c = threadIdx.x;
    for (int k = 0; k < 32; k++) {
        float wv = (k < N_RBF) ? fw1[k * H + c] : 0.f;
        unsigned short hi = f2bf(wv);
        unsigned short lo = f2bf(wv - bf2f(hi));
        fw1t2[c * 64 + k] = hi;
        fw1t2[c * 64 + 32 + k] = lo;
    }
}

// ---------------- counting sort by idx_i ----------------
__global__ __launch_bounds__(256) void k_hist(const int* __restrict__ idx_i,
                                              int* __restrict__ counts) {
    int e = blockIdx.x * 256 + threadIdx.x;
    if (e < N_EDGES) atomicAdd(&counts[idx_i[e]], 1);
}
__global__ __launch_bounds__(256) void k_scan(const int* __restrict__ counts,
                                              int* __restrict__ rowstart) {
    __shared__ int part[257];
    int t = threadIdx.x;
    const int PER = 40;
    int s = 0;
    for (int r = 0; r < PER; ++r) { int i = t * PER + r; if (i < N_ATOMS) s += counts[i]; }
    part[t + 1] = s;
    if (t == 0) part[0] = 0;
    __syncthreads();
    for (int off = 1; off < 256; off <<= 1) {
        int v = (t + 1 > off) ? part[t + 1 - off] : 0;
        __syncthreads();
        part[t + 1] += v;
        __syncthreads();
    }
    int run = part[t];
    for (int r = 0; r < PER; ++r) {
        int i = t * PER + r;
        if (i < N_ATOMS) { rowstart[i] = run; run += counts[i]; }
    }
    if (t == 255) rowstart[N_ATOMS] = run;
}
__global__ __launch_bounds__(256) void k_scatter(const int* __restrict__ idx_i,
                                                 const int* __restrict__ rowstart,
                                                 int* __restrict__ cursor,
                                                 int* __restrict__ perm) {
    int e = blockIdx.x * 256 + threadIdx.x;
    if (e >= N_EDGES) return;
    int i = idx_i[e];
    int p = rowstart[i] + atomicAdd(&cursor[i], 1);
    perm[p] = e;
}
__global__ __launch_bounds__(256) void k_gather(const int* __restrict__ perm,
                                                const int* __restrict__ idx_i,
                                                const int* __restrict__ idx_j,
                                                const float* __restrict__ f_cut,
                                                const float* __restrict__ dir_ij,
                                                const float* __restrict__ inv_ptr,
                                                int* __restrict__ si, int* __restrict__ sj,
                                                float* __restrict__ sfc,
                                                float* __restrict__ sdir) {
    int p = blockIdx.x * 256 + threadIdx.x;
    if (p >= N_EDGES) return;
    int e = perm[p];
    si[p] = idx_i[e];
    sj[p] = idx_j[e];
    sfc[p] = f_cut[e] * inv_ptr[0];
    sdir[p * 3 + 0] = dir_ij[e * 3 + 0];
    sdir[p * 3 + 1] = dir_ij[e * 3 + 1];
    sdir[p * 3 + 2] = dir_ij[e * 3 + 2];
}

// ---------------- fused edge kernel (R7 + occupancy push) ----------------
// Grid (2500, 8): 128 sorted edges x 96-row col-tile (32 cols x 3 segs).
// LDS 28KB (single s_w) -> 5 blocks/CU; launch_bounds(256,5) forces regs
// under the 5-wave/SIMD budget (acc 48 AGPR + ~54 VGPR). h-gen 2-term
// (fw1 exact, rbf bf16-hi). Main GEMM 2-term (w_hi+w_lo)*h_hi. Prefetch
// issued after visibility barrier, consumed next iteration.
__global__ __launch_bounds__(256, 5) void k_edge(
    const int* __restrict__ perm, const float* __restrict__ rbf,
    const int* __restrict__ si, const int* __restrict__ sj,
    const float* __restrict__ sfc, const float* __restrict__ sdir,
    const unsigned short* __restrict__ fw1t2, const float* __restrict__ fb1,
    const unsigned short* __restrict__ fw2t2, const float* __restrict__ fb2,
    const float* __restrict__ ctx, const float* __restrict__ v_in,
    float* __restrict__ out_s, float* __restrict__ out_v) {
    __shared__ char sm[28672];
    char* s_h = sm;                 // [128 e][128B] h-hi (swz (e&7)<<4), 16KB
    char* s_w = sm + 16384;         // [96 n][128B] hi|lo (swz (n&7)<<4), 12KB

    int tid = threadIdx.x;
    int lane = tid & 63, w = tid >> 6;
    int l16 = lane & 15, g4 = lane >> 4;
    int e0 = blockIdx.x * 128;
    int ct = blockIdx.y;

    // ---- rbf fragments in registers (bf16-hi only), per ef ----
    bf16x8 bfr_hi[2];
#pragma unroll
    for (int ef = 0; ef < 2; ++ef) {
        int pe = perm[e0 + 32 * w + 16 * ef + l16];
        const float* rr = rbf + (size_t)pe * N_RBF;
        float x[8];
#pragma unroll
        for (int t = 0; t < 8; ++t) x[t] = 0.f;
        if (g4 == 0) {
            float4 a = *(const float4*)(rr);
            float4 b = *(const float4*)(rr + 4);
            x[0]=a.x; x[1]=a.y; x[2]=a.z; x[3]=a.w;
            x[4]=b.x; x[5]=b.y; x[6]=b.z; x[7]=b.w;
        } else if (g4 == 1) {
            float4 a = *(const float4*)(rr + 8);
            float4 b = *(const float4*)(rr + 12);
            x[0]=a.x; x[1]=a.y; x[2]=a.z; x[3]=a.w;
            x[4]=b.x; x[5]=b.y; x[6]=b.z; x[7]=b.w;
        } else if (g4 == 2) {
            float4 a = *(const float4*)(rr + 16);
            x[0]=a.x; x[1]=a.y; x[2]=a.z; x[3]=a.w;
        }
        union { bf16x8 v; unsigned short s[8]; } uh;
#pragma unroll
        for (int t = 0; t < 8; ++t) uh.s[t] = f2bf(x[t]);
        bfr_hi[ef] = uh.v;
    }

    f32x4 acc[6][2];
#pragma unroll
    for (int a = 0; a < 6; a++)
#pragma unroll
        for (int b = 0; b < 2; b++) acc[a][b] = (f32x4){0.f, 0.f, 0.f, 0.f};

    // ---- preload W tile q=0 ----
    uint4 wreg[3];
#pragma unroll
    for (int r = 0; r < 3; ++r) {
        int u = tid + 256 * r;
        int n = u >> 3, sl = u & 7;
        int n_glob = (n >> 5) * 256 + ct * 32 + (n & 31);
        int koff = (sl < 4) ? sl * 8 : 256 + (sl - 4) * 8;
        wreg[r] = *(const uint4*)(fw2t2 + (size_t)n_glob * 512 + koff);
    }

    for (int q = 0; q < 8; ++q) {
        __syncthreads();            // WAR: all waves done reading s_w (q-1);
                                    // also drains last iter's prefetch
        // (a) write current W tile from wreg
#pragma unroll
        for (int r = 0; r < 3; ++r) {
            int u = tid + 256 * r;
            int n = u >> 3, sl = u & 7;
            *(uint4*)(s_w + n * 128 + ((sl * 16) ^ ((n & 7) << 4))) = wreg[r];
        }
        __syncthreads();            // visibility of s_w
        // (b) issue next W tile AFTER barrier (consumed next iteration;
        //     latency covered by h-gen + MFMA below)
        if (q < 7) {
#pragma unroll
            for (int r = 0; r < 3; ++r) {
                int u = tid + 256 * r;
                int n = u >> 3, sl = u & 7;
                int n_glob = (n >> 5) * 256 + ct * 32 + (n & 31);
                int koff = (sl < 4) ? ((q + 1) * 32 + sl * 8)
                                    : (256 + (q + 1) * 32 + (sl - 4) * 8);
                wreg[r] = *(const uint4*)(fw2t2 + (size_t)n_glob * 512 + koff);
            }
        }
        // (c) h chunk via 2-term split MFMA (fw1 hi+lo, rbf hi), hi-only store
#pragma unroll
        for (int cf = 0; cf < 2; ++cf) {
            const unsigned short* ar = fw1t2 + (size_t)(q * 32 + cf * 16 + l16) * 64;
            bf16x8 ahi = *(const bf16x8*)(ar + g4 * 8);
            bf16x8 alo = *(const bf16x8*)(ar + 32 + g4 * 8);
            int cbase = cf * 16 + g4 * 4;
            float4 b1 = *(const float4*)(fb1 + q * 32 + cbase);
#pragma unroll
            for (int ef = 0; ef < 2; ++ef) {
                f32x4 ha = (f32x4){0.f, 0.f, 0.f, 0.f};
                ha = MFMA16(ahi, bfr_hi[ef], ha, 0, 0, 0);
                ha = MFMA16(alo, bfr_hi[ef], ha, 0, 0, 0);
                float h0 = silu_f(ha[0] + b1.x);
                float h1 = silu_f(ha[1] + b1.y);
                float h2 = silu_f(ha[2] + b1.z);
                float h3 = silu_f(ha[3] + b1.w);
                uint2 pk;
                pk.x = (unsigned)f2bf(h0) | ((unsigned)f2bf(h1) << 16);
                pk.y = (unsigned)f2bf(h2) | ((unsigned)f2bf(h3) << 16);
                int e = 32 * w + 16 * ef + l16;
                *(uint2*)(s_h + e * 128 + ((2 * cbase) ^ ((e & 7) << 4))) = pk;
            }
        }
        // (d) main MFMA: 2-term, 6 n-frags x 2 e-frags
        bf16x8 bh[2];
#pragma unroll
        for (int ef = 0; ef < 2; ef++) {
            int e = 32 * w + 16 * ef + l16;
            bh[ef] = *(const bf16x8*)(s_h + e * 128 + ((16 * g4) ^ ((e & 7) << 4)));
        }
#pragma unroll
        for (int nf = 0; nf < 6; nf++) {
            int n = nf * 16 + l16;
            int swzn = (n & 7) << 4;
            bf16x8 aw_hi = *(const bf16x8*)(s_w + n * 128 + ((16 * g4) ^ swzn));
            bf16x8 aw_lo = *(const bf16x8*)(s_w + n * 128 + ((64 + 16 * g4) ^ swzn));
#pragma unroll
            for (int ef = 0; ef < 2; ef++) {
                acc[nf][ef] = MFMA16(aw_hi, bh[ef], acc[nf][ef], 0, 0, 0);
                acc[nf][ef] = MFMA16(aw_lo, bh[ef], acc[nf][ef], 0, 0, 0);
            }
        }
    }

    // ---------------- epilogue (verbatim R4/R7) ----------------
#pragma unroll
    for (int ef = 0; ef < 2; ++ef) {
        int E = e0 + 32 * w + 16 * ef + l16;
        int ai = si[E], aj = sj[E];
        float fc = sfc[E];
        float d0 = sdir[3 * E], d1 = sdir[3 * E + 1], d2 = sdir[3 * E + 2];
        int i1 = __shfl_down(ai, 1, 16), i2 = __shfl_down(ai, 2, 16);
        int i4 = __shfl_down(ai, 4, 16), i8 = __shfl_down(ai, 8, 16);
        int prevai = __shfl_up(ai, 1, 16);
        bool m1 = (l16 + 1 < 16) && (i1 == ai);
        bool m2 = (l16 + 2 < 16) && (i2 == ai);
        bool m4 = (l16 + 4 < 16) && (i4 == ai);
        bool m8 = (l16 + 8 < 16) && (i8 == ai);
        bool lead = (l16 == 0) || (prevai != ai);
        const float* cj = ctx + (size_t)aj * H3;
        const float* vj = v_in + (size_t)aj * H3;
#pragma unroll
        for (int ci = 0; ci < 2; ++ci) {
            int Cb = ct * 32 + ci * 16 + g4 * 4;
            float4 c0 = *(const float4*)(cj + Cb);
            float4 c1 = *(const float4*)(cj + H + Cb);
            float4 c2 = *(const float4*)(cj + 2 * H + Cb);
            float4 u0 = *(const float4*)(vj + Cb);
            float4 u1 = *(const float4*)(vj + H + Cb);
            float4 u2 = *(const float4*)(vj + 2 * H + Cb);
            float4 b0 = *(const float4*)(fb2 + Cb);
            float4 b1 = *(const float4*)(fb2 + H + Cb);
            float4 b2 = *(const float4*)(fb2 + 2 * H + Cb);
            float vds[4], vv0[4], vv1[4], vv2[4];
#pragma unroll
            for (int r = 0; r < 4; ++r) {
                float w0 = acc[ci][ef][r]     + ((const float*)&b0)[r];
                float w1 = acc[2 + ci][ef][r] + ((const float*)&b1)[r];
                float w2 = acc[4 + ci][ef][r] + ((const float*)&b2)[r];
                float ds  = ((const float*)&c0)[r] * w0 * fc;
                float dvs = ((const float*)&c1)[r] * w1 * fc;
                float dvv = ((const float*)&c2)[r] * w2 * fc;
                vds[r] = ds;
                vv0[r] = dvs * d0 + dvv * ((const float*)&u0)[r];
                vv1[r] = dvs * d1 + dvv * ((const float*)&u1)[r];
                vv2[r] = dvs * d2 + dvv * ((const float*)&u2)[r];
            }
#pragma unroll
            for (int st = 0; st < 4; ++st) {
                int off = 1 << st;
                bool m = (st == 0) ? m1 : (st == 1) ? m2 : (st == 2) ? m4 : m8;
#pragma unroll
                for (int r = 0; r < 4; ++r) {
                    float t0 = __shfl_down(vds[r], off, 16);
                    float t1 = __shfl_down(vv0[r], off, 16);
                    float t2 = __shfl_down(vv1[r], off, 16);
                    float t3 = __shfl_down(vv2[r], off, 16);
                    if (m) { vds[r] += t0; vv0[r] += t1; vv1[r] += t2; vv2[r] += t3; }
                }
            }
            if (lead) {
#pragma unroll
                for (int r = 0; r < 4; ++r) {
                    int C = Cb + r;
                    atomicAdd(&out_s[(size_t)ai * H + C], vds[r]);
                    atomicAdd(&out_v[(size_t)ai * H3 + C], vv0[r]);
                    atomicAdd(&out_v[(size_t)ai * H3 + H + C], vv1[r]);
                    atomicAdd(&out_v[(size_t)ai * H3 + 2 * H + C], vv2[r]);
                }
            }
        }
    }
}

extern "C" void kernel_launch(void* const* d_in, const int* in_sizes, int n_in,
                              void* d_out, int out_size, void* d_ws, size_t ws_size,
                              hipStream_t stream) {
    const float* s      = (const float*)d_in[0];
    const float* v      = (const float*)d_in[1];
    const int*   idx_i  = (const int*)d_in[2];
    const int*   idx_j  = (const int*)d_in[3];
    const float* rbf    = (const float*)d_in[4];
    const float* f_cut  = (const float*)d_in[5];
    const float* dir_ij = (const float*)d_in[6];
    const float* inv    = (const float*)d_in[7];
    const float* ln_g   = (const float*)d_in[8];
    const float* ln_b   = (const float*)d_in[9];
    const float* cw1    = (const float*)d_in[10];
    const float* cb1    = (const float*)d_in[11];
    const float* cw2    = (const float*)d_in[12];
    const float* cb2    = (const float*)d_in[13];
    const float* fw1    = (const float*)d_in[14];
    const float* fb1    = (const float*)d_in[15];
    const float* fw2    = (const float*)d_in[16];
    const float* fb2    = (const float*)d_in[17];

    float* out_s = (float*)d_out;
    float* out_v = out_s + (size_t)N_ATOMS * H;

    // ---- ws layout (bytes), peak 47,022,080 (< 51.2MB proven) ----
    char* wsb = (char*)d_ws;
    unsigned short* fw2t2    = (unsigned short*)(wsb + 0);          //    786,432
    unsigned short* fw1t2    = (unsigned short*)(wsb + 786432);     //     32,768
    int*            counts   = (int*)(wsb + 819200);                //     40,960
    int*            rowstart = (int*)(wsb + 860160);                //     40,960
    int*            cursor   = (int*)(wsb + 901120);                //     40,960
    float*          ctx      = (float*)(wsb + 942080);              // 30,720,000 fp32
    float*          sn       = (float*)(wsb + 31662080);            // 10,240,000
    unsigned short* ctx1     = (unsigned short*)(wsb + 41902080);   //  5,120,000 bf16
    // overlays of sn region (written only after gemm1 consumed sn):
    int*            perm     = (int*)(wsb + 31662080);              //  1,280,000
    int*            si       = (int*)(wsb + 32942080);
    int*            sj       = (int*)(wsb + 34222080);
    float*          sfc      = (float*)(wsb + 35502080);
    float*          sdir     = (float*)(wsb + 36782080);            //  3,840,000

    // init outputs with s, v (updates accumulated atomically on top)
    hipMemcpyAsync(out_s, s, sizeof(float) * (size_t)N_ATOMS * H,
                   hipMemcpyDeviceToDevice, stream);
    hipMemcpyAsync(out_v, v, sizeof(float) * (size_t)N_ATOMS * 3 * H,
                   hipMemcpyDeviceToDevice, stream);
    hipMemsetAsync(counts, 0, 122880, stream);   // counts+rowstart+cursor

    // weight prep + histogram
    k_prep_fw2t2<<<768, 256, 0, stream>>>(fw2, fw2t2);
    k_prep_fw1t2<<<1, 256, 0, stream>>>(fw1, fw1t2);
    k_hist<<<(N_EDGES + 255) / 256, 256, 0, stream>>>(idx_i, counts);
    k_scan<<<1, 256, 0, stream>>>(counts, rowstart);

    // context path (uses sn, then ctx1, then ctx)
    k_ln<<<N_ATOMS, 256, 0, stream>>>(s, ln_g, ln_b, sn);
    dim3 g1((N_ATOMS + 63) / 64, H / 64);
    k_gemm<1, 0, 1><<<g1, 256, 0, stream>>>(sn, cw1, cb1, ctx1, N_ATOMS, H, H);

    // sort outputs overlay sn (dead now)
    k_scatter<<<(N_EDGES + 255) / 256, 256, 0, stream>>>(idx_i, rowstart, cursor, perm);
    k_gather<<<(N_EDGES + 255) / 256, 256, 0, stream>>>(
        perm, idx_i, idx_j, f_cut, dir_ij, inv, si, sj, sfc, sdir);

    dim3 g2((N_ATOMS + 63) / 64, H3 / 64);
    k_gemm<0, 1, 0><<<g2, 256, 0, stream>>>(ctx1, cw2, cb2, ctx, N_ATOMS, H3, H);

    // fused edge GEMM + scatter
    dim3 ge(N_EDGES / 128, 8);
    k_edge<<<ge, 256, 0, stream>>>(perm, rbf, si, sj, sfc, sdir, fw1t2, fb1,
                                   fw2t2, fb2, ctx, v, out_s, out_v);
}

// Round 9
// 1386.216 us; speedup vs baseline: 1.1544x; 1.1544x over previous
//
#include <hip/hip_runtime.h>
#include <hip/hip_bf16.h>

#define N_ATOMS 10000
#define N_EDGES 320000
#define H 256
#define H3 768
#define N_RBF 20
#define LN_EPS 1e-5f

typedef __attribute__((ext_vector_type(8))) short bf16x8;
typedef __attribute__((ext_vector_type(4))) float f32x4;
#define MFMA16 __builtin_amdgcn_mfma_f32_16x16x32_bf16

__device__ __forceinline__ float silu_f(float x) { return x / (1.f + __expf(-x)); }

__device__ __forceinline__ unsigned short f2bf(float x) {
    union { float f; unsigned u; } v; v.f = x;
    unsigned r = v.u + 0x7fff + ((v.u >> 16) & 1);
    return (unsigned short)(r >> 16);
}
__device__ __forceinline__ float bf2f(unsigned short b) {
    union { unsigned u; float f; } v; v.u = ((unsigned)b) << 16; return v.f;
}

// ---------------- LayerNorm: one block (256 thr) per atom ----------------
__global__ __launch_bounds__(256) void k_ln(const float* __restrict__ s,
                                            const float* __restrict__ g,
                                            const float* __restrict__ b,
                                            float* __restrict__ sn) {
    int a = blockIdx.x, t = threadIdx.x;
    float x = s[(size_t)a * H + t];
    __shared__ float red[4];
    float v = x;
    for (int o = 32; o > 0; o >>= 1) v += __shfl_down(v, o);
    if ((t & 63) == 0) red[t >> 6] = v;
    __syncthreads();
    float mu = (red[0] + red[1] + red[2] + red[3]) * (1.f / H);
    float dx = x - mu;
    __syncthreads();
    v = dx * dx;
    for (int o = 32; o > 0; o >>= 1) v += __shfl_down(v, o);
    if ((t & 63) == 0) red[t >> 6] = v;
    __syncthreads();
    float var = (red[0] + red[1] + red[2] + red[3]) * (1.f / H);
    float rs = rsqrtf(var + LN_EPS);
    sn[(size_t)a * H + t] = dx * rs * g[t] + b[t];
}

// ---------------- fp32 tiled GEMM: C = [silu](A@B + bias) ----------------
template <int DO_SILU, int IN_BF16, int OUT_BF16>
__global__ __launch_bounds__(256) void k_gemm(const void* __restrict__ Av,
                                              const float* __restrict__ B,
                                              const float* __restrict__ bias,
                                              void* __restrict__ Cv,
                                              int M, int N, int K) {
    const int BM = 64, BN = 64, BK = 16;
    __shared__ float As[BK][BM + 1];
    __shared__ float Bs[BK][BN + 1];
    int tid = threadIdx.x;
    int m0 = blockIdx.x * BM, n0 = blockIdx.y * BN;
    int ty = tid >> 4, tx = tid & 15;
    float acc[4][4] = {};
    for (int k0 = 0; k0 < K; k0 += BK) {
        {
            int kk = tid & 15, mm = tid >> 4;
            for (int r = 0; r < 4; r++) {
                int m = mm + r * 16;
                int gm = m0 + m;
                float a = 0.f;
                if (gm < M) {
                    if (IN_BF16) a = bf2f(((const unsigned short*)Av)[(size_t)gm * K + k0 + kk]);
                    else         a = ((const float*)Av)[(size_t)gm * K + k0 + kk];
                }
                As[kk][m] = a;
            }
        }
        {
            int n = tid & 63, kk = tid >> 6;
            for (int r = 0; r < 4; r++) {
                int k = kk + r * 4;
                Bs[k][n] = B[(size_t)(k0 + k) * N + n0 + n];
            }
        }
        __syncthreads();
        for (int k = 0; k < BK; k++) {
            float a[4], bb[4];
            for (int i = 0; i < 4; i++) a[i] = As[k][ty * 4 + i];
            for (int j = 0; j < 4; j++) bb[j] = Bs[k][tx * 4 + j];
            for (int i = 0; i < 4; i++)
                for (int j = 0; j < 4; j++) acc[i][j] += a[i] * bb[j];
        }
        __syncthreads();
    }
    for (int i = 0; i < 4; i++) {
        int gm = m0 + ty * 4 + i;
        if (gm >= M) continue;
        for (int j = 0; j < 4; j++) {
            int gn = n0 + tx * 4 + j;
            float y = acc[i][j] + bias[gn];
            if (DO_SILU) y = silu_f(y);
            if (OUT_BF16) ((unsigned short*)Cv)[(size_t)gm * N + gn] = f2bf(y);
            else          ((float*)Cv)[(size_t)gm * N + gn] = y;
        }
    }
}

// ---------------- weight prep ----------------
__global__ __launch_bounds__(256) void k_prep_fw2t2(const float* __restrict__ fw2,
                                                    unsigned short* __restrict__ fw2t2) {
    int n = blockIdx.x, k = threadIdx.x;
    float wv = fw2[(size_t)k * H3 + n];
    unsigned short hi = f2bf(wv);
    unsigned short lo = f2bf(wv - bf2f(hi));
    fw2t2[(size_t)n * 512 + k] = hi;
    fw2t2[(size_t)n * 512 + 256 + k] = lo;
}
__global__ __launch_bounds__(256) void k_prep_fw1t2(const float* __restrict__ fw1,
                                                    unsigned short* __restrict__ fw1t2) {
    int c = threadIdx.x;
    for (int k = 0; k < 32; k++) {
        float wv = (k < N_RBF) ? fw1[k * H + c] : 0.f;
        unsigned short hi = f2bf(wv);
        unsigned short lo = f2bf(wv - bf2f(hi));
        fw1t2[c * 64 + k] = hi;
        fw1t2[c * 64 + 32 + k] = lo;
    }
}

// ---------------- counting sort by idx_i ----------------
__global__ __launch_bounds__(256) void k_hist(const int* __restrict__ idx_i,
                                              int* __restrict__ counts) {
    int e = blockIdx.x * 256 + threadIdx.x;
    if (e < N_EDGES) atomicAdd(&counts[idx_i[e]], 1);
}
__global__ __launch_bounds__(256) void k_scan(const int* __restrict__ counts,
                                              int* __restrict__ rowstart) {
    __shared__ int part[257];
    int t = threadIdx.x;
    const int PER = 40;
    int s = 0;
    for (int r = 0; r < PER; ++r) { int i = t * PER + r; if (i < N_ATOMS) s += counts[i]; }
    part[t + 1] = s;
    if (t == 0) part[0] = 0;
    __syncthreads();
    for (int off = 1; off < 256; off <<= 1) {
        int v = (t + 1 > off) ? part[t + 1 - off] : 0;
        __syncthreads();
        part[t + 1] += v;
        __syncthreads();
    }
    int run = part[t];
    for (int r = 0; r < PER; ++r) {
        int i = t * PER + r;
        if (i < N_ATOMS) { rowstart[i] = run; run += counts[i]; }
    }
    if (t == 255) rowstart[N_ATOMS] = run;
}
__global__ __launch_bounds__(256) void k_scatter(const int* __restrict__ idx_i,
                                                 const int* __restrict__ rowstart,
                                                 int* __restrict__ cursor,
                                                 int* __restrict__ perm) {
    int e = blockIdx.x * 256 + threadIdx.x;
    if (e >= N_EDGES) return;
    int i = idx_i[e];
    int p = rowstart[i] + atomicAdd(&cursor[i], 1);
    perm[p] = e;
}
__global__ __launch_bounds__(256) void k_gather(const int* __restrict__ perm,
                                                const int* __restrict__ idx_i,
                                                const int* __restrict__ idx_j,
                                                const float* __restrict__ f_cut,
                                                const float* __restrict__ dir_ij,
                                                const float* __restrict__ inv_ptr,
                                                int* __restrict__ si, int* __restrict__ sj,
                                                float* __restrict__ sfc,
                                                float* __restrict__ sdir) {
    int p = blockIdx.x * 256 + threadIdx.x;
    if (p >= N_EDGES) return;
    int e = perm[p];
    si[p] = idx_i[e];
    sj[p] = idx_j[e];
    sfc[p] = f_cut[e] * inv_ptr[0];
    sdir[p * 3 + 0] = dir_ij[e * 3 + 0];
    sdir[p * 3 + 1] = dir_ij[e * 3 + 1];
    sdir[p * 3 + 2] = dir_ij[e * 3 + 2];
}

// ---------------- fused edge kernel (CB=64, XCD-grouped) -----------------
// 1-D grid 10016. Decode: xcd lane x=id&7 owns a CONTIGUOUS range of the
// 2500 edge-groups; m=id>>3 enumerates (group_local, ct) with the 4 ct-
// blocks of each group dispatch-adjacent on the same XCD (id = x + 8m).
// Block: 128 sorted edges x 64-col tile (192 W rows, 3 segs). Main loop =
// R8 pattern (single s_w, prefetch-after-barrier, 2-term h-gen, 2-term W).
__global__ __launch_bounds__(256, 3) void k_edge(
    const int* __restrict__ perm, const float* __restrict__ rbf,
    const int* __restrict__ si, const int* __restrict__ sj,
    const float* __restrict__ sfc, const float* __restrict__ sdir,
    const unsigned short* __restrict__ fw1t2, const float* __restrict__ fb1,
    const unsigned short* __restrict__ fw2t2, const float* __restrict__ fb2,
    const float* __restrict__ ctx, const float* __restrict__ v_in,
    float* __restrict__ out_s, float* __restrict__ out_v) {
    __shared__ char sm[40960];
    char* s_h = sm;                 // [128 e][128B] h-hi (swz (e&7)<<4), 16KB
    char* s_w = sm + 16384;         // [192 n][128B] hi|lo (swz (n&7)<<4), 24KB

    int id = blockIdx.x;
    int x = id & 7, m = id >> 3;
    int ct = m & 3, gl = m >> 2;
    int cap = 312 + (x < 4 ? 1 : 0);
    if (gl >= cap) return;
    int g = x * 312 + (x < 4 ? x : 4) + gl;

    int tid = threadIdx.x;
    int lane = tid & 63, w = tid >> 6;
    int l16 = lane & 15, g4 = lane >> 4;
    int e0 = g * 128;

    // ---- rbf fragments in registers (bf16-hi), per ef ----
    bf16x8 bfr_hi[2];
#pragma unroll
    for (int ef = 0; ef < 2; ++ef) {
        int pe = perm[e0 + 32 * w + 16 * ef + l16];
        const float* rr = rbf + (size_t)pe * N_RBF;
        float xx[8];
#pragma unroll
        for (int t = 0; t < 8; ++t) xx[t] = 0.f;
        if (g4 == 0) {
            float4 a = *(const float4*)(rr);
            float4 b = *(const float4*)(rr + 4);
            xx[0]=a.x; xx[1]=a.y; xx[2]=a.z; xx[3]=a.w;
            xx[4]=b.x; xx[5]=b.y; xx[6]=b.z; xx[7]=b.w;
        } else if (g4 == 1) {
            float4 a = *(const float4*)(rr + 8);
            float4 b = *(const float4*)(rr + 12);
            xx[0]=a.x; xx[1]=a.y; xx[2]=a.z; xx[3]=a.w;
            xx[4]=b.x; xx[5]=b.y; xx[6]=b.z; xx[7]=b.w;
        } else if (g4 == 2) {
            float4 a = *(const float4*)(rr + 16);
            xx[0]=a.x; xx[1]=a.y; xx[2]=a.z; xx[3]=a.w;
        }
        union { bf16x8 v; unsigned short s[8]; } uh;
#pragma unroll
        for (int t = 0; t < 8; ++t) uh.s[t] = f2bf(xx[t]);
        bfr_hi[ef] = uh.v;
    }

    f32x4 acc[12][2];
#pragma unroll
    for (int a = 0; a < 12; a++)
#pragma unroll
        for (int b = 0; b < 2; b++) acc[a][b] = (f32x4){0.f, 0.f, 0.f, 0.f};

    // ---- preload W tile q=0: 192 rows x 8 slots = 6 uint4/thread ----
    uint4 wreg[6];
#pragma unroll
    for (int r = 0; r < 6; ++r) {
        int u = tid + 256 * r;
        int n = u >> 3, sl = u & 7;
        int n_glob = (n >> 6) * 256 + ct * 64 + (n & 63);
        int koff = (sl < 4) ? sl * 8 : 256 + (sl - 4) * 8;
        wreg[r] = *(const uint4*)(fw2t2 + (size_t)n_glob * 512 + koff);
    }

    for (int q = 0; q < 8; ++q) {
        __syncthreads();            // WAR: all waves done reading s_w (q-1)
#pragma unroll
        for (int r = 0; r < 6; ++r) {
            int u = tid + 256 * r;
            int n = u >> 3, sl = u & 7;
            *(uint4*)(s_w + n * 128 + ((sl * 16) ^ ((n & 7) << 4))) = wreg[r];
        }
        __syncthreads();            // visibility of s_w
        if (q < 7) {                // prefetch next tile AFTER barrier
#pragma unroll
            for (int r = 0; r < 6; ++r) {
                int u = tid + 256 * r;
                int n = u >> 3, sl = u & 7;
                int n_glob = (n >> 6) * 256 + ct * 64 + (n & 63);
                int koff = (sl < 4) ? ((q + 1) * 32 + sl * 8)
                                    : (256 + (q + 1) * 32 + (sl - 4) * 8);
                wreg[r] = *(const uint4*)(fw2t2 + (size_t)n_glob * 512 + koff);
            }
        }
        // h chunk via 2-term split MFMA (fw1 hi+lo, rbf hi), hi-only store
#pragma unroll
        for (int cf = 0; cf < 2; ++cf) {
            const unsigned short* ar = fw1t2 + (size_t)(q * 32 + cf * 16 + l16) * 64;
            bf16x8 ahi = *(const bf16x8*)(ar + g4 * 8);
            bf16x8 alo = *(const bf16x8*)(ar + 32 + g4 * 8);
            int cbase = cf * 16 + g4 * 4;
            float4 b1 = *(const float4*)(fb1 + q * 32 + cbase);
#pragma unroll
            for (int ef = 0; ef < 2; ++ef) {
                f32x4 ha = (f32x4){0.f, 0.f, 0.f, 0.f};
                ha = MFMA16(ahi, bfr_hi[ef], ha, 0, 0, 0);
                ha = MFMA16(alo, bfr_hi[ef], ha, 0, 0, 0);
                float h0 = silu_f(ha[0] + b1.x);
                float h1 = silu_f(ha[1] + b1.y);
                float h2 = silu_f(ha[2] + b1.z);
                float h3 = silu_f(ha[3] + b1.w);
                uint2 pk;
                pk.x = (unsigned)f2bf(h0) | ((unsigned)f2bf(h1) << 16);
                pk.y = (unsigned)f2bf(h2) | ((unsigned)f2bf(h3) << 16);
                int e = 32 * w + 16 * ef + l16;
                *(uint2*)(s_h + e * 128 + ((2 * cbase) ^ ((e & 7) << 4))) = pk;
            }
        }
        // main MFMA: 2-term, 12 n-frags x 2 e-frags
        bf16x8 bh[2];
#pragma unroll
        for (int ef = 0; ef < 2; ef++) {
            int e = 32 * w + 16 * ef + l16;
            bh[ef] = *(const bf16x8*)(s_h + e * 128 + ((16 * g4) ^ ((e & 7) << 4)));
        }
#pragma unroll
        for (int nf = 0; nf < 12; nf++) {
            int n = nf * 16 + l16;
            int swzn = (n & 7) << 4;
            bf16x8 aw_hi = *(const bf16x8*)(s_w + n * 128 + ((16 * g4) ^ swzn));
            bf16x8 aw_lo = *(const bf16x8*)(s_w + n * 128 + ((64 + 16 * g4) ^ swzn));
#pragma unroll
            for (int ef = 0; ef < 2; ef++) {
                acc[nf][ef] = MFMA16(aw_hi, bh[ef], acc[nf][ef], 0, 0, 0);
                acc[nf][ef] = MFMA16(aw_lo, bh[ef], acc[nf][ef], 0, 0, 0);
            }
        }
    }

    // ---------------- epilogue (R3-style, 4 ci per leader) ----------------
#pragma unroll
    for (int ef = 0; ef < 2; ++ef) {
        int E = e0 + 32 * w + 16 * ef + l16;
        int ai = si[E], aj = sj[E];
        float fc = sfc[E];
        float d0 = sdir[3 * E], d1 = sdir[3 * E + 1], d2 = sdir[3 * E + 2];
        int i1 = __shfl_down(ai, 1, 16), i2 = __shfl_down(ai, 2, 16);
        int i4 = __shfl_down(ai, 4, 16), i8 = __shfl_down(ai, 8, 16);
        int prevai = __shfl_up(ai, 1, 16);
        bool m1 = (l16 + 1 < 16) && (i1 == ai);
        bool m2 = (l16 + 2 < 16) && (i2 == ai);
        bool m4 = (l16 + 4 < 16) && (i4 == ai);
        bool m8 = (l16 + 8 < 16) && (i8 == ai);
        bool lead = (l16 == 0) || (prevai != ai);
        const float* cj = ctx + (size_t)aj * H3;
        const float* vj = v_in + (size_t)aj * H3;
#pragma unroll
        for (int ci = 0; ci < 4; ++ci) {
            int Cb = ct * 64 + ci * 16 + g4 * 4;
            float4 c0 = *(const float4*)(cj + Cb);
            float4 c1 = *(const float4*)(cj + H + Cb);
            float4 c2 = *(const float4*)(cj + 2 * H + Cb);
            float4 u0 = *(const float4*)(vj + Cb);
            float4 u1 = *(const float4*)(vj + H + Cb);
            float4 u2 = *(const float4*)(vj + 2 * H + Cb);
            float4 b0 = *(const float4*)(fb2 + Cb);
            float4 b1 = *(const float4*)(fb2 + H + Cb);
            float4 b2 = *(const float4*)(fb2 + 2 * H + Cb);
            float vds[4], vv0[4], vv1[4], vv2[4];
#pragma unroll
            for (int r = 0; r < 4; ++r) {
                float w0 = acc[ci][ef][r]     + ((const float*)&b0)[r];
                float w1 = acc[4 + ci][ef][r] + ((const float*)&b1)[r];
                float w2 = acc[8 + ci][ef][r] + ((const float*)&b2)[r];
                float ds  = ((const float*)&c0)[r] * w0 * fc;
                float dvs = ((const float*)&c1)[r] * w1 * fc;
                float dvv = ((const float*)&c2)[r] * w2 * fc;
                vds[r] = ds;
                vv0[r] = dvs * d0 + dvv * ((const float*)&u0)[r];
                vv1[r] = dvs * d1 + dvv * ((const float*)&u1)[r];
                vv2[r] = dvs * d2 + dvv * ((const float*)&u2)[r];
            }
#pragma unroll
            for (int st = 0; st < 4; ++st) {
                int off = 1 << st;
                bool mm = (st == 0) ? m1 : (st == 1) ? m2 : (st == 2) ? m4 : m8;
#pragma unroll
                for (int r = 0; r < 4; ++r) {
                    float t0 = __shfl_down(vds[r], off, 16);
                    float t1 = __shfl_down(vv0[r], off, 16);
                    float t2 = __shfl_down(vv1[r], off, 16);
                    float t3 = __shfl_down(vv2[r], off, 16);
                    if (mm) { vds[r] += t0; vv0[r] += t1; vv1[r] += t2; vv2[r] += t3; }
                }
            }
            if (lead) {
#pragma unroll
                for (int r = 0; r < 4; ++r) {
                    int C = Cb + r;
                    atomicAdd(&out_s[(size_t)ai * H + C], vds[r]);
                    atomicAdd(&out_v[(size_t)ai * H3 + C], vv0[r]);
                    atomicAdd(&out_v[(size_t)ai * H3 + H + C], vv1[r]);
                    atomicAdd(&out_v[(size_t)ai * H3 + 2 * H + C], vv2[r]);
                }
            }
        }
    }
}

extern "C" void kernel_launch(void* const* d_in, const int* in_sizes, int n_in,
                              void* d_out, int out_size, void* d_ws, size_t ws_size,
                              hipStream_t stream) {
    const float* s      = (const float*)d_in[0];
    const float* v      = (const float*)d_in[1];
    const int*   idx_i  = (const int*)d_in[2];
    const int*   idx_j  = (const int*)d_in[3];
    const float* rbf    = (const float*)d_in[4];
    const float* f_cut  = (const float*)d_in[5];
    const float* dir_ij = (const float*)d_in[6];
    const float* inv    = (const float*)d_in[7];
    const float* ln_g   = (const float*)d_in[8];
    const float* ln_b   = (const float*)d_in[9];
    const float* cw1    = (const float*)d_in[10];
    const float* cb1    = (const float*)d_in[11];
    const float* cw2    = (const float*)d_in[12];
    const float* cb2    = (const float*)d_in[13];
    const float* fw1    = (const float*)d_in[14];
    const float* fb1    = (const float*)d_in[15];
    const float* fw2    = (const float*)d_in[16];
    const float* fb2    = (const float*)d_in[17];

    float* out_s = (float*)d_out;
    float* out_v = out_s + (size_t)N_ATOMS * H;

    // ---- ws layout (bytes), peak 47,022,080 (< 51.2MB proven) ----
    char* wsb = (char*)d_ws;
    unsigned short* fw2t2    = (unsigned short*)(wsb + 0);          //    786,432
    unsigned short* fw1t2    = (unsigned short*)(wsb + 786432);     //     32,768
    int*            counts   = (int*)(wsb + 819200);                //     40,960
    int*            rowstart = (int*)(wsb + 860160);                //     40,960
    int*            cursor   = (int*)(wsb + 901120);                //     40,960
    float*          ctx      = (float*)(wsb + 942080);              // 30,720,000 fp32
    float*          sn       = (float*)(wsb + 31662080);            // 10,240,000
    unsigned short* ctx1     = (unsigned short*)(wsb + 41902080);   //  5,120,000 bf16
    // overlays of sn region (written only after gemm1 consumed sn):
    int*            perm     = (int*)(wsb + 31662080);              //  1,280,000
    int*            si       = (int*)(wsb + 32942080);
    int*            sj       = (int*)(wsb + 34222080);
    float*          sfc      = (float*)(wsb + 35502080);
    float*          sdir     = (float*)(wsb + 36782080);            //  3,840,000

    // init outputs with s, v (updates accumulated atomically on top)
    hipMemcpyAsync(out_s, s, sizeof(float) * (size_t)N_ATOMS * H,
                   hipMemcpyDeviceToDevice, stream);
    hipMemcpyAsync(out_v, v, sizeof(float) * (size_t)N_ATOMS * 3 * H,
                   hipMemcpyDeviceToDevice, stream);
    hipMemsetAsync(counts, 0, 122880, stream);   // counts+rowstart+cursor

    // weight prep + histogram
    k_prep_fw2t2<<<768, 256, 0, stream>>>(fw2, fw2t2);
    k_prep_fw1t2<<<1, 256, 0, stream>>>(fw1, fw1t2);
    k_hist<<<(N_EDGES + 255) / 256, 256, 0, stream>>>(idx_i, counts);
    k_scan<<<1, 256, 0, stream>>>(counts, rowstart);

    // context path (uses sn, then ctx1, then ctx)
    k_ln<<<N_ATOMS, 256, 0, stream>>>(s, ln_g, ln_b, sn);
    dim3 g1((N_ATOMS + 63) / 64, H / 64);
    k_gemm<1, 0, 1><<<g1, 256, 0, stream>>>(sn, cw1, cb1, ctx1, N_ATOMS, H, H);

    // sort outputs overlay sn (dead now)
    k_scatter<<<(N_EDGES + 255) / 256, 256, 0, stream>>>(idx_i, rowstart, cursor, perm);
    k_gather<<<(N_EDGES + 255) / 256, 256, 0, stream>>>(
        perm, idx_i, idx_j, f_cut, dir_ij, inv, si, sj, sfc, sdir);

    dim3 g2((N_ATOMS + 63) / 64, H3 / 64);
    k_gemm<0, 1, 0><<<g2, 256, 0, stream>>>(ctx1, cw2, cb2, ctx, N_ATOMS, H3, H);

    // fused edge GEMM + scatter (1-D grid, XCD-grouped decode)
    k_edge<<<10016, 256, 0, stream>>>(perm, rbf, si, sj, sfc, sdir, fw1t2, fb1,
                                      fw2t2, fb2, ctx, v, out_s, out_v);
}